// Round 3
// baseline (371.905 us; speedup 1.0000x reference)
//
#include <hip/hip_runtime.h>
#include <stdint.h>

#define NS 32
#define NIN 2048
#define NOUT 2048

// ---------- Threefry-2x32 (20 rounds), exact JAX semantics ----------
__device__ __forceinline__ uint32_t rotl32(uint32_t v, uint32_t r) {
    return __builtin_amdgcn_alignbit(v, v, 32u - r);
}

#define TF_R(x0, x1, r)          \
    do {                         \
        x0 += x1;                \
        x1 = rotl32(x1, r) ^ x0; \
    } while (0)

// x1in = counter + k1 (pre-added). Injection constants are wave-uniform -> SGPR.
__device__ __forceinline__ uint32_t tf_fold(uint32_t k0, uint32_t k1, uint32_t k2,
                                            uint32_t x1in) {
    uint32_t x0 = k0 + x1in;
    uint32_t x1 = rotl32(x1in, 13) ^ x0;
    TF_R(x0, x1, 15); TF_R(x0, x1, 26); TF_R(x0, x1, 6);
    x0 += k1; x1 += k2 + 1u;
    TF_R(x0, x1, 17); TF_R(x0, x1, 29); TF_R(x0, x1, 16); TF_R(x0, x1, 24);
    x0 += k2; x1 += k0 + 2u;
    TF_R(x0, x1, 13); TF_R(x0, x1, 15); TF_R(x0, x1, 26); TF_R(x0, x1, 6);
    x0 += k0; x1 += k1 + 3u;
    TF_R(x0, x1, 17); TF_R(x0, x1, 29); TF_R(x0, x1, 16); TF_R(x0, x1, 24);
    x0 += k1; x1 += k2 + 4u;
    TF_R(x0, x1, 13); TF_R(x0, x1, 15); TF_R(x0, x1, 26); TF_R(x0, x1, 6);
    x0 += k2; x1 += k0 + 5u;
    return x0 ^ x1;
}

// bits -> uniform(-1+2^-24, 1) -> sqrt(2)*erfinv (XLA/Giles polynomial)
__device__ __forceinline__ float normal_from_bits(uint32_t bits) {
    const float LO = __uint_as_float(0xBF7FFFFFu);  // nextafter(-1.f, 0.f)
    float f = __uint_as_float((bits >> 9) | 0x3f800000u) - 1.0f;  // [0,1)
    float u = fmaf(f, 2.0f, LO);             // f>=0 => max(LO,.) is identity
    float w = -__logf(fmaf(-u, u, 1.0f));    // -log1p(-u*u)
    float p;
    if (w < 5.0f) {
        w -= 2.5f;
        p = 2.81022636e-08f;
        p = fmaf(p, w, 3.43273939e-07f);
        p = fmaf(p, w, -3.5233877e-06f);
        p = fmaf(p, w, -4.39150654e-06f);
        p = fmaf(p, w, 0.00021858087f);
        p = fmaf(p, w, -0.00125372503f);
        p = fmaf(p, w, -0.00417768164f);
        p = fmaf(p, w, 0.246640727f);
        p = fmaf(p, w, 1.50140941f);
    } else {
        w = __fsqrt_rn(w) - 3.0f;
        p = -0.000200214257f;
        p = fmaf(p, w, 0.000100950558f);
        p = fmaf(p, w, 0.00134934322f);
        p = fmaf(p, w, -0.00367342844f);
        p = fmaf(p, w, 0.00573950773f);
        p = fmaf(p, w, -0.0076224613f);
        p = fmaf(p, w, 0.00943887047f);
        p = fmaf(p, w, 1.00167406f);
        p = fmaf(p, w, 2.83297682f);
    }
    return 1.41421356237f * p * u;  // sqrt(2) * erfinv(u)
}

// Block = output row o. Thread (s = tid&31, g = tid>>5) accumulates a scalar
// partial over i in [g*256, g*256+256). 4 independent hash chains per iter
// (float4-wide) -> ILP hides VALU dep latency; scalar acc frees VGPRs.
__global__ __launch_bounds__(256, 4) void bayes_linear_kernel(
    const float* __restrict__ x, const float* __restrict__ wmu,
    const float* __restrict__ wsg, const float* __restrict__ bmu,
    const float* __restrict__ bsg, float* __restrict__ out,
    uint32_t kw0, uint32_t kw1, uint32_t kb0, uint32_t kb1) {
    const int o = blockIdx.x;
    const int tid = threadIdx.x;
    const int s = tid & 31;
    const int g = tid >> 5;

    const uint32_t kw2 = kw0 ^ kw1 ^ 0x1BD11BDAu;
    const uint32_t kb2 = kb0 ^ kb1 ^ 0x1BD11BDAu;

    const uint32_t baseo = (uint32_t)o * NIN;
    const uint32_t ibase = (uint32_t)g * (NIN / 8);  // 256-wide chunk
    // threefry counter p = s*OUT*IN + o*IN + i; pre-add k1 (x1 += k1)
    const uint32_t pb0 = (uint32_t)s * (uint32_t)(NOUT * NIN) + baseo + ibase + kw1;

    const float4* __restrict__ wmu4 = (const float4*)(wmu + baseo + ibase);
    const float4* __restrict__ wsg4 = (const float4*)(wsg + baseo + ibase);
    const float4* __restrict__ xp4  = (const float4*)(x + (uint32_t)s * NIN + ibase);

    float acc0 = 0.0f, acc1 = 0.0f;
    for (int it = 0; it < NIN / 8 / 4; ++it) {  // 64 iters x 4 elems
        const float4 m4 = wmu4[it];
        const float4 g4 = wsg4[it];
        const float4 xv = xp4[it];
        const uint32_t p = pb0 + (uint32_t)(it * 4);
        // 4 independent threefry chains -> scheduler interleaves them
        const uint32_t b0 = tf_fold(kw0, kw1, kw2, p + 0u);
        const uint32_t b1 = tf_fold(kw0, kw1, kw2, p + 1u);
        const uint32_t b2 = tf_fold(kw0, kw1, kw2, p + 2u);
        const uint32_t b3 = tf_fold(kw0, kw1, kw2, p + 3u);
        const float e0 = normal_from_bits(b0);
        const float e1 = normal_from_bits(b1);
        const float e2 = normal_from_bits(b2);
        const float e3 = normal_from_bits(b3);
        acc0 = fmaf(fmaf(g4.x, e0, m4.x), xv.x, acc0);
        acc1 = fmaf(fmaf(g4.y, e1, m4.y), xv.y, acc1);
        acc0 = fmaf(fmaf(g4.z, e2, m4.z), xv.z, acc0);
        acc1 = fmaf(fmaf(g4.w, e3, m4.w), xv.w, acc1);
    }

    __shared__ float red[8][NS];
    red[g][s] = acc0 + acc1;
    __syncthreads();

    if (tid < NS) {
        const int ss = tid;
        float sum = 0.0f;
#pragma unroll
        for (int gg = 0; gg < 8; ++gg) sum += red[gg][ss];
        // bias eps: flat index into (S, OUT): s*OUT + o
        const uint32_t pb = (uint32_t)(ss * NOUT + o) + kb1;
        const float eb = normal_from_bits(tf_fold(kb0, kb1, kb2, pb));
        out[ss * NOUT + o] = sum + fmaf(bsg[o], eb, bmu[o]);
    }
}

// ---------- host-side threefry for key derivation ----------
#define TF_ROUND_H(x0, x1, r)                     \
    do {                                          \
        x0 += x1;                                 \
        x1 = (x1 << (r)) | (x1 >> (32 - (r)));    \
        x1 ^= x0;                                 \
    } while (0)

static void tf2x32_host(uint32_t k0, uint32_t k1, uint32_t x0, uint32_t x1,
                        uint32_t* y0, uint32_t* y1) {
    uint32_t k2 = k0 ^ k1 ^ 0x1BD11BDAu;
    x0 += k0; x1 += k1;
    TF_ROUND_H(x0, x1, 13); TF_ROUND_H(x0, x1, 15); TF_ROUND_H(x0, x1, 26); TF_ROUND_H(x0, x1, 6);
    x0 += k1; x1 += k2 + 1u;
    TF_ROUND_H(x0, x1, 17); TF_ROUND_H(x0, x1, 29); TF_ROUND_H(x0, x1, 16); TF_ROUND_H(x0, x1, 24);
    x0 += k2; x1 += k0 + 2u;
    TF_ROUND_H(x0, x1, 13); TF_ROUND_H(x0, x1, 15); TF_ROUND_H(x0, x1, 26); TF_ROUND_H(x0, x1, 6);
    x0 += k0; x1 += k1 + 3u;
    TF_ROUND_H(x0, x1, 17); TF_ROUND_H(x0, x1, 29); TF_ROUND_H(x0, x1, 16); TF_ROUND_H(x0, x1, 24);
    x0 += k1; x1 += k2 + 4u;
    TF_ROUND_H(x0, x1, 13); TF_ROUND_H(x0, x1, 15); TF_ROUND_H(x0, x1, 26); TF_ROUND_H(x0, x1, 6);
    x0 += k2; x1 += k0 + 5u;
    *y0 = x0; *y1 = x1;
}

extern "C" void kernel_launch(void* const* d_in, const int* in_sizes, int n_in,
                              void* d_out, int out_size, void* d_ws, size_t ws_size,
                              hipStream_t stream) {
    const float* x   = (const float*)d_in[0];
    const float* wmu = (const float*)d_in[1];
    const float* wsg = (const float*)d_in[2];
    const float* bmu = (const float*)d_in[3];
    const float* bsg = (const float*)d_in[4];
    float* out = (float*)d_out;

    uint32_t kw0, kw1, kb0, kb1;
    tf2x32_host(0u, 42u, 0u, 0u, &kw0, &kw1);  // wkey = split(key(42))[0]
    tf2x32_host(0u, 42u, 0u, 1u, &kb0, &kb1);  // bkey = split(key(42))[1]

    bayes_linear_kernel<<<NOUT, 256, 0, stream>>>(x, wmu, wsg, bmu, bsg, out,
                                                  kw0, kw1, kb0, kb1);
}

// Round 4
// 338.064 us; speedup vs baseline: 1.1001x; 1.1001x over previous
//
#include <hip/hip_runtime.h>
#include <stdint.h>

#define NS 32
#define NIN 2048
#define NOUT 2048

// ================= Threefry-2x32, 4 independent chains in hand-scheduled asm =================
// rot r == v_alignbit_b32(v,v,32-r). Rotation schedule 13,15,26,6 / 17,29,16,24
// -> shift immediates 19,17,6,26 / 15,3,16,8 (all inline constants, free).
// State: a_i = x1 (enters holding counter+k1), t_i = x0. Keys/injections in SGPRs.

#define ADD4                                 \
    "v_add_u32 %[t0], %[t0], %[a0]\n\t"      \
    "v_add_u32 %[t1], %[t1], %[a1]\n\t"      \
    "v_add_u32 %[t2], %[t2], %[a2]\n\t"      \
    "v_add_u32 %[t3], %[t3], %[a3]\n\t"

#define ADDK4                                \
    "v_add_u32 %[t0], %[k0], %[a0]\n\t"      \
    "v_add_u32 %[t1], %[k0], %[a1]\n\t"      \
    "v_add_u32 %[t2], %[k0], %[a2]\n\t"      \
    "v_add_u32 %[t3], %[k0], %[a3]\n\t"

#define ROT4(sh)                                          \
    "v_alignbit_b32 %[a0], %[a0], %[a0], " sh "\n\t"      \
    "v_alignbit_b32 %[a1], %[a1], %[a1], " sh "\n\t"      \
    "v_alignbit_b32 %[a2], %[a2], %[a2], " sh "\n\t"      \
    "v_alignbit_b32 %[a3], %[a3], %[a3], " sh "\n\t"

#define XOR4                                 \
    "v_xor_b32 %[a0], %[a0], %[t0]\n\t"      \
    "v_xor_b32 %[a1], %[a1], %[t1]\n\t"      \
    "v_xor_b32 %[a2], %[a2], %[t2]\n\t"      \
    "v_xor_b32 %[a3], %[a3], %[t3]\n\t"

#define TF4R(sh) ADD4 ROT4(sh) XOR4

#define TF4INJ(ka, kb)                           \
    "v_add_u32 %[t0], %[" ka "], %[t0]\n\t"      \
    "v_add_u32 %[t1], %[" ka "], %[t1]\n\t"      \
    "v_add_u32 %[t2], %[" ka "], %[t2]\n\t"      \
    "v_add_u32 %[t3], %[" ka "], %[t3]\n\t"      \
    "v_add_u32 %[a0], %[" kb "], %[a0]\n\t"      \
    "v_add_u32 %[a1], %[" kb "], %[a1]\n\t"      \
    "v_add_u32 %[a2], %[" kb "], %[a2]\n\t"      \
    "v_add_u32 %[a3], %[" kb "], %[a3]\n\t"

// a_i in: counter+k1.  a_i out: x0^x1 (the folded bits).
__device__ __forceinline__ void tf_fold4(uint32_t k0, uint32_t k1, uint32_t k2,
                                         uint32_t& a0, uint32_t& a1,
                                         uint32_t& a2, uint32_t& a3) {
    uint32_t t0, t1, t2, t3;
    const uint32_t c1 = k2 + 1u, c2 = k0 + 2u, c3 = k1 + 3u, c4 = k2 + 4u, c5 = k0 + 5u;
    asm volatile(
        // rounds 1-4 (rot 13,15,26,6)
        ADDK4 ROT4("19") XOR4
        TF4R("17") TF4R("6") TF4R("26")
        TF4INJ("k1", "c1")
        // rounds 5-8 (rot 17,29,16,24)
        TF4R("15") TF4R("3") TF4R("16") TF4R("8")
        TF4INJ("k2", "c2")
        // rounds 9-12
        TF4R("19") TF4R("17") TF4R("6") TF4R("26")
        TF4INJ("k0", "c3")
        // rounds 13-16
        TF4R("15") TF4R("3") TF4R("16") TF4R("8")
        TF4INJ("k1", "c4")
        // rounds 17-20
        TF4R("19") TF4R("17") TF4R("6") TF4R("26")
        TF4INJ("k2", "c5")
        // fold x0^x1
        XOR4
        : [a0] "+v"(a0), [a1] "+v"(a1), [a2] "+v"(a2), [a3] "+v"(a3),
          [t0] "=&v"(t0), [t1] "=&v"(t1), [t2] "=&v"(t2), [t3] "=&v"(t3)
        : [k0] "s"(k0), [k1] "s"(k1), [k2] "s"(k2),
          [c1] "s"(c1), [c2] "s"(c2), [c3] "s"(c3), [c4] "s"(c4), [c5] "s"(c5));
}

// ---------- bits -> uniform(-1+2^-24,1) -> w = -log(1-u^2) ----------
__device__ __forceinline__ void uw_from_bits(uint32_t bits, float& u, float& w) {
    const float LO = __uint_as_float(0xBF7FFFFFu);  // nextafter(-1.f, 0.f)
    float f = __uint_as_float((bits >> 9) | 0x3f800000u) - 1.0f;  // [0,1)
    u = fmaf(f, 2.0f, LO);            // >= LO always
    w = -__logf(fmaf(-u, u, 1.0f));   // -log1p(-u*u)
}

__device__ __forceinline__ float erfinv_p_fast(float w) {  // w < 5
    float t = w - 2.5f;
    float p = 2.81022636e-08f;
    p = fmaf(p, t, 3.43273939e-07f);
    p = fmaf(p, t, -3.5233877e-06f);
    p = fmaf(p, t, -4.39150654e-06f);
    p = fmaf(p, t, 0.00021858087f);
    p = fmaf(p, t, -0.00125372503f);
    p = fmaf(p, t, -0.00417768164f);
    p = fmaf(p, t, 0.246640727f);
    p = fmaf(p, t, 1.50140941f);
    return p;
}

__device__ __forceinline__ float erfinv_p_slow(float w) {  // w >= 5
    float t = __fsqrt_rn(w) - 3.0f;
    float p = -0.000200214257f;
    p = fmaf(p, t, 0.000100950558f);
    p = fmaf(p, t, 0.00134934322f);
    p = fmaf(p, t, -0.00367342844f);
    p = fmaf(p, t, 0.00573950773f);
    p = fmaf(p, t, -0.0076224613f);
    p = fmaf(p, t, 0.00943887047f);
    p = fmaf(p, t, 1.00167406f);
    p = fmaf(p, t, 2.83297682f);
    return p;
}

__device__ __forceinline__ float normal_from_bits(uint32_t bits) {  // scalar (bias path)
    float u, w;
    uw_from_bits(bits, u, w);
    float p = (w < 5.0f) ? erfinv_p_fast(w) : erfinv_p_slow(w);
    return 1.41421356237f * p * u;
}

// Block = output row o. Thread (s = tid&31, g = tid>>5): scalar partial over
// i in [g*256, g*256+256), 4 eps per iteration via the asm 4-chain hash.
__global__ __launch_bounds__(256, 2) void bayes_linear_kernel(
    const float* __restrict__ x, const float* __restrict__ wmu,
    const float* __restrict__ wsg, const float* __restrict__ bmu,
    const float* __restrict__ bsg, float* __restrict__ out,
    uint32_t kw0, uint32_t kw1, uint32_t kb0, uint32_t kb1) {
    const int o = blockIdx.x;
    const int tid = threadIdx.x;
    const int s = tid & 31;
    const int g = tid >> 5;

    const uint32_t kw2 = kw0 ^ kw1 ^ 0x1BD11BDAu;
    const uint32_t kb2 = kb0 ^ kb1 ^ 0x1BD11BDAu;

    const uint32_t baseo = (uint32_t)o * NIN;
    const uint32_t ibase = (uint32_t)g * (NIN / 8);
    const uint32_t pb0 = (uint32_t)s * (uint32_t)(NOUT * NIN) + baseo + ibase + kw1;

    const float4* __restrict__ wmu4 = (const float4*)(wmu + baseo + ibase);
    const float4* __restrict__ wsg4 = (const float4*)(wsg + baseo + ibase);
    const float4* __restrict__ xp4  = (const float4*)(x + (uint32_t)s * NIN + ibase);

    float acc0 = 0.0f, acc1 = 0.0f;
    for (int it = 0; it < NIN / 8 / 4; ++it) {  // 64 iters x 4 eps
        const float4 m4 = wmu4[it];
        const float4 g4 = wsg4[it];
        const float4 xv = xp4[it];

        const uint32_t p = pb0 + (uint32_t)(it * 4);
        uint32_t b0 = p + 0u, b1 = p + 1u, b2 = p + 2u, b3 = p + 3u;
        tf_fold4(kw0, kw1, kw2, b0, b1, b2, b3);

        float u0, u1, u2, u3, w0, w1, w2, w3;
        uw_from_bits(b0, u0, w0);
        uw_from_bits(b1, u1, w1);
        uw_from_bits(b2, u2, w2);
        uw_from_bits(b3, u3, w3);
        float p0 = erfinv_p_fast(w0);
        float p1 = erfinv_p_fast(w1);
        float p2 = erfinv_p_fast(w2);
        float p3 = erfinv_p_fast(w3);
        // slow erfinv tail: ~0.07% of lanes; skip whole block for 95.6% of waves
        if (__any(fmaxf(fmaxf(w0, w1), fmaxf(w2, w3)) >= 5.0f)) {
            if (w0 >= 5.0f) p0 = erfinv_p_slow(w0);
            if (w1 >= 5.0f) p1 = erfinv_p_slow(w1);
            if (w2 >= 5.0f) p2 = erfinv_p_slow(w2);
            if (w3 >= 5.0f) p3 = erfinv_p_slow(w3);
        }
        const float e0 = 1.41421356237f * p0 * u0;
        const float e1 = 1.41421356237f * p1 * u1;
        const float e2 = 1.41421356237f * p2 * u2;
        const float e3 = 1.41421356237f * p3 * u3;

        acc0 = fmaf(fmaf(g4.x, e0, m4.x), xv.x, acc0);
        acc1 = fmaf(fmaf(g4.y, e1, m4.y), xv.y, acc1);
        acc0 = fmaf(fmaf(g4.z, e2, m4.z), xv.z, acc0);
        acc1 = fmaf(fmaf(g4.w, e3, m4.w), xv.w, acc1);
    }

    __shared__ float red[8][NS];
    red[g][s] = acc0 + acc1;
    __syncthreads();

    if (tid < NS) {
        const int ss = tid;
        float sum = 0.0f;
#pragma unroll
        for (int gg = 0; gg < 8; ++gg) sum += red[gg][ss];
        const uint32_t pb = (uint32_t)(ss * NOUT + o) + kb1;
        uint32_t b0 = pb, b1 = pb, b2 = pb, b3 = pb;  // reuse 4-chain for 1 value
        tf_fold4(kb0, kb1, kb2, b0, b1, b2, b3);
        const float eb = normal_from_bits(b0);
        out[ss * NOUT + o] = sum + fmaf(bsg[o], eb, bmu[o]);
    }
}

// ---------- host-side threefry for key derivation ----------
#define TF_ROUND_H(x0, x1, r)                     \
    do {                                          \
        x0 += x1;                                 \
        x1 = (x1 << (r)) | (x1 >> (32 - (r)));    \
        x1 ^= x0;                                 \
    } while (0)

static void tf2x32_host(uint32_t k0, uint32_t k1, uint32_t x0, uint32_t x1,
                        uint32_t* y0, uint32_t* y1) {
    uint32_t k2 = k0 ^ k1 ^ 0x1BD11BDAu;
    x0 += k0; x1 += k1;
    TF_ROUND_H(x0, x1, 13); TF_ROUND_H(x0, x1, 15); TF_ROUND_H(x0, x1, 26); TF_ROUND_H(x0, x1, 6);
    x0 += k1; x1 += k2 + 1u;
    TF_ROUND_H(x0, x1, 17); TF_ROUND_H(x0, x1, 29); TF_ROUND_H(x0, x1, 16); TF_ROUND_H(x0, x1, 24);
    x0 += k2; x1 += k0 + 2u;
    TF_ROUND_H(x0, x1, 13); TF_ROUND_H(x0, x1, 15); TF_ROUND_H(x0, x1, 26); TF_ROUND_H(x0, x1, 6);
    x0 += k0; x1 += k1 + 3u;
    TF_ROUND_H(x0, x1, 17); TF_ROUND_H(x0, x1, 29); TF_ROUND_H(x0, x1, 16); TF_ROUND_H(x0, x1, 24);
    x0 += k1; x1 += k2 + 4u;
    TF_ROUND_H(x0, x1, 13); TF_ROUND_H(x0, x1, 15); TF_ROUND_H(x0, x1, 26); TF_ROUND_H(x0, x1, 6);
    x0 += k2; x1 += k0 + 5u;
    *y0 = x0; *y1 = x1;
}

extern "C" void kernel_launch(void* const* d_in, const int* in_sizes, int n_in,
                              void* d_out, int out_size, void* d_ws, size_t ws_size,
                              hipStream_t stream) {
    const float* x   = (const float*)d_in[0];
    const float* wmu = (const float*)d_in[1];
    const float* wsg = (const float*)d_in[2];
    const float* bmu = (const float*)d_in[3];
    const float* bsg = (const float*)d_in[4];
    float* out = (float*)d_out;

    uint32_t kw0, kw1, kb0, kb1;
    tf2x32_host(0u, 42u, 0u, 0u, &kw0, &kw1);  // wkey = split(key(42))[0]
    tf2x32_host(0u, 42u, 0u, 1u, &kb0, &kb1);  // bkey = split(key(42))[1]

    bayes_linear_kernel<<<NOUT, 256, 0, stream>>>(x, wmu, wsg, bmu, bsg, out,
                                                  kw0, kw1, kb0, kb1);
}